// Round 11
// baseline (250.418 us; speedup 1.0000x reference)
//
#include <hip/hip_runtime.h>

// SnConv3: B=8, N=32, C=64, O=64
#define NBATCH 8
#define NN 32
#define NC 64
#define NO 64
#define C6 384
#define C10 640
#define C12 768
#define C5 320

typedef __attribute__((ext_vector_type(8))) short short8;   // 8 bf16 (4 VGPRs)
typedef __attribute__((ext_vector_type(4))) float float4v;  // 4 fp32

// workspace layout (float offsets)
static constexpr int OFF_ABF = 0;        // a2 bf16 [8][32][32][384] = 1,572,864 floats
static constexpr int OFF_A1  = 1572864;  // [8][32][640] f32        =   163,840
static constexpr int OFF_A0  = 1736704;  // [8][320] f32            =     2,560
static constexpr int OFF_R1  = 1739264;  // [3][8][32][64]          =    49,152
static constexpr int OFF_R1T = 1788416;  // [3][8][32][64]          =    49,152
static constexpr int OFF_R0  = 1837568;  // [3][8][64]              =     1,536
static constexpr int OFF_MD  = 1839104;  // [8][32][64]             =    16,384
static constexpr int OFF_WB  = 1855488;  // W33 bf16 frags: 24576 sh =   12,288
static constexpr int OFF_WB2 = 1867776;  // W22 bf16 frags: 147456 sh=   73,728
// total 1,941,504 floats ~= 7.8 MB

__device__ __forceinline__ unsigned short f2bf(float f) {
    union { float f; unsigned u; } x{f};
    unsigned r = x.u + 0x7fffu + ((x.u >> 16) & 1u);  // RNE
    return (unsigned short)(r >> 16);
}

__device__ __forceinline__ void store_bf4(unsigned short* p, float4v v) {
    ushort4 w;
    w.x = f2bf(v.x); w.y = f2bf(v.y); w.z = f2bf(v.z); w.w = f2bf(v.w);
    *(ushort4*)p = w;
}

__device__ __forceinline__ float4v bf4(const unsigned short* p) {
    ushort4 u = *(const ushort4*)(p);
    float4v r;
    r.x = __uint_as_float((unsigned)u.x << 16);
    r.y = __uint_as_float((unsigned)u.y << 16);
    r.z = __uint_as_float((unsigned)u.z << 16);
    r.w = __uint_as_float((unsigned)u.w << 16);
    return r;
}

// ---------------------------------------------------------------------------
// K_prep2: fused weight-prep (blocks 0..83) + a2 contraction (blocks 84..1619).
// R9 post-mortem: contraction was latency-bound (VALUBusy 4.6%, Occ ~10%,
// 99 loads/thread, VGPR 148). NOW split 3 ways by sum-axis: class 0 = s1+d12,
// class 1 = s2+d13, class 2 = s3+d23. 3x the threads, 33 loads/thread, same
// total traffic, disjoint a2 chunk writes, block-uniform class (no wave div).
// ---------------------------------------------------------------------------
__global__ __launch_bounds__(256) void k_prep2(const float* __restrict__ W33,
                                               const float* __restrict__ W22,
                                               const float* __restrict__ x,
                                               float* __restrict__ ws) {
    if (blockIdx.x < 84) {
        // ---- weight prep: W33/W22 f32 -> bf16 B-fragments ----
        int id = blockIdx.x * 256 + threadIdx.x;  // 21504
        if (id < 3072) {                          // W33: nt(4) x ks(12) x lane(64)
            int lane = id & 63;
            int ks = (id >> 6) % 12;
            int nt = (id >> 6) / 12;
            int n = nt * 16 + (lane & 15);
            int k0 = ks * 32 + (lane >> 4) * 8;
            unsigned short* dst = (unsigned short*)(ws + OFF_WB) +
                                  (size_t)((nt * 12 + ks) * 64 + lane) * 8;
#pragma unroll
            for (int jj = 0; jj < 8; ++jj) dst[jj] = f2bf(W33[(k0 + jj) * 64 + n]);
        } else if (id < 21504) {                  // W22: i(3) x nt(4) x ks(24) x lane(64)
            int q = id - 3072;
            int lane = q & 63;
            int ks = (q >> 6) % 24;
            int r = (q >> 6) / 24;
            int nt = r & 3;
            int i = r >> 2;
            int n = nt * 16 + (lane & 15);
            int k0 = ks * 32 + (lane >> 4) * 8;
            const float* W = W22 + (size_t)i * C12 * NO;
            unsigned short* dst = (unsigned short*)(ws + OFF_WB2) +
                                  (size_t)(((i * 4 + nt) * 24 + ks) * 64 + lane) * 8;
#pragma unroll
            for (int jj = 0; jj < 8; ++jj) dst[jj] = f2bf(W[(k0 + jj) * 64 + n]);
        }
        return;
    }
    // ---- a2 (bf16), 3-way axis split ----
    int qb = blockIdx.x - 84;              // 0..1535
    int cls = qb >> 9;                     // 0,1,2 (block-uniform)
    int id = (qb & 511) * 256 + threadIdx.x;  // 0..131071
    int c4 = id & 15;
    int v = (id >> 4) & 31;
    int u = (id >> 9) & 31;
    int b = id >> 14;
    int bc = c4 * 4;
    const float* xb = x + (size_t)b * 2097152;
    unsigned short* a2 = (unsigned short*)(ws + OFF_ABF) +
                         (size_t)((b * 32 + u) * 32 + v) * C6 + bc;
    const float inv = 1.0f / 32.0f;
    float4v s = {0.f, 0.f, 0.f, 0.f};

    if (cls == 0) {            // s1 = mean over axis1: x[b,i,u,v,c] ; d12 = x[b,v,v,u,c]
        const float* p = xb + u * 2048 + v * 64 + bc;
        for (int i = 0; i < 32; ++i) s += *(const float4v*)(p + i * 65536);
        float4v d12 = *(const float4v*)(xb + v * 65536 + v * 2048 + u * 64 + bc);
        store_bf4(a2 + 0 * 64, s * inv);
        store_bf4(a2 + 3 * 64, d12);
    } else if (cls == 1) {     // s2 = mean over axis2: x[b,u,j,v,c] ; d13 = x[b,v,u,v,c]
        const float* p = xb + u * 65536 + v * 64 + bc;
        for (int j = 0; j < 32; ++j) s += *(const float4v*)(p + j * 2048);
        float4v d13 = *(const float4v*)(xb + v * 65536 + u * 2048 + v * 64 + bc);
        store_bf4(a2 + 1 * 64, s * inv);
        store_bf4(a2 + 4 * 64, d13);
    } else {                   // s3 = mean over axis3: x[b,u,v,k,c] ; d23 = x[b,u,v,v,c]
        const float* p = xb + u * 65536 + v * 2048 + bc;
        for (int k = 0; k < 32; ++k) s += *(const float4v*)(p + k * 64);
        float4v d23 = *(const float4v*)(xb + u * 65536 + v * 2048 + v * 64 + bc);
        store_bf4(a2 + 2 * 64, s * inv);
        store_bf4(a2 + 5 * 64, d23);
    }
}

// ---------------------------------------------------------------------------
// K_contract1: a1 from bf16 a2 + triple diagonal, a0 atomics (pre-zeroed).
// Block per (b,t): 256 blocks x 256 threads. (Benched form, unchanged.)
// ---------------------------------------------------------------------------
__global__ __launch_bounds__(256) void k_contract1(const float* __restrict__ x,
                                                   float* __restrict__ ws) {
    __shared__ float4v red[16][148];  // [q][ch*16+c4], 4-f4 pad per q
    int blk = blockIdx.x;             // b*32 + t
    int b = blk >> 5;
    int t = blk & 31;
    int tid = threadIdx.x;
    int c4 = tid & 15;
    int q = tid >> 4;                 // 0..15
    int bc = c4 * 4;
    const unsigned short* a2 = (const unsigned short*)(ws + OFF_ABF) +
                               (size_t)b * 32 * 32 * C6;

    float4v pu0 = {0.f, 0.f, 0.f, 0.f};
    float4v pu3 = pu0, pu4 = pu0, pu5 = pu0;
    float4v pv0 = pu0, pv1 = pu0, pv3 = pu0, pv4 = pu0, pv5 = pu0;
#pragma unroll
    for (int s = 0; s < 2; ++s) {
        int u = q * 2 + s;
        const unsigned short* rU = a2 + (size_t)(u * 32 + t) * C6 + bc;
        const unsigned short* rV = a2 + (size_t)(t * 32 + u) * C6 + bc;
        pu0 += bf4(rU + 0);
        pu3 += bf4(rU + 192);
        pu4 += bf4(rU + 256);
        pu5 += bf4(rU + 320);
        pv0 += bf4(rV + 0);
        pv1 += bf4(rV + 64);
        pv3 += bf4(rV + 192);
        pv4 += bf4(rV + 256);
        pv5 += bf4(rV + 320);
    }
    // a1 chunk order: 0:su0 1:sv0 2:sv1 3:su3 4:sv3 5:su4 6:sv4 7:su5 8:sv5 9:td
    red[q][0 * 16 + c4] = pu0;
    red[q][1 * 16 + c4] = pv0;
    red[q][2 * 16 + c4] = pv1;
    red[q][3 * 16 + c4] = pu3;
    red[q][4 * 16 + c4] = pv3;
    red[q][5 * 16 + c4] = pu4;
    red[q][6 * 16 + c4] = pv4;
    red[q][7 * 16 + c4] = pu5;
    red[q][8 * 16 + c4] = pv5;
    __syncthreads();

    const float inv = 1.0f / 32.0f;
    float* a1 = ws + OFF_A1 + ((size_t)b * 32 + t) * C10;
    float* a0 = ws + OFF_A0 + (size_t)b * C5;
    if (tid < 144) {                  // 9 chunks x 16 c4
        int ch = tid >> 4;
        int cc = tid & 15;
        float4v s = {0.f, 0.f, 0.f, 0.f};
#pragma unroll
        for (int qq = 0; qq < 16; ++qq) s += red[qq][ch * 16 + cc];
        s *= inv;
        *(float4v*)(a1 + ch * 64 + cc * 4) = s;
        // a0 chunks: a1 {0,3,5,7} -> a0 {0,1,2,3}
        int aidx = (ch == 0) ? 0 : (ch == 3) ? 1 : (ch == 5) ? 2 : (ch == 7) ? 3 : -1;
        if (aidx >= 0) {
#pragma unroll
            for (int e = 0; e < 4; ++e)
                atomicAdd(a0 + aidx * 64 + cc * 4 + e, s[e] * inv);
        }
    } else if (tid < 160) {           // triple diagonal -> a1 chunk 9 + a0 chunk 4
        int cc = tid - 144;
        float4v td = *(const float4v*)(x + (((size_t)b * 32 + t) * 32 + t) * 2048 +
                                       t * 64 + cc * 4);
        *(float4v*)(a1 + 9 * 64 + cc * 4) = td;
#pragma unroll
        for (int e = 0; e < 4; ++e)
            atomicAdd(a0 + 4 * 64 + cc * 4 + e, td[e] * inv);
    }
}

// ---------------------------------------------------------------------------
// K_rowmix: r1, r1t, mdiag, r0 via 116K independent threads (TLP-optimal).
// ---------------------------------------------------------------------------
__global__ __launch_bounds__(256) void k_rowmix(
    const float* __restrict__ W12, const float* __restrict__ b12,
    const float* __restrict__ W12t, const float* __restrict__ b12t,
    const float* __restrict__ W02, const float* __restrict__ b02,
    const float* __restrict__ W11, const float* __restrict__ b11,
    const float* __restrict__ W01, const float* __restrict__ b01,
    float* __restrict__ ws) {
    int id = blockIdx.x * 256 + threadIdx.x;
    if (id < 98304) {  // r1 / r1t
        bool second = id >= 49152;
        int q = second ? id - 49152 : id;
        int o = q & 63;
        int t = (q >> 6) & 31;
        int b = (q >> 11) & 7;
        int i = q >> 14;
        const float* W = (second ? W12t : W12) + (size_t)i * C10 * NO;
        const float* bb = (second ? b12t : b12) + i * NO;
        const float* a1 = ws + OFF_A1 + ((size_t)b * 32 + t) * C10;
        float acc = bb[o];
        for (int m = 0; m < C10; ++m) acc += a1[m] * W[m * NO + o];
        ws[(second ? OFF_R1T : OFF_R1) + (((size_t)i * 8 + b) * 32 + t) * NO + o] = acc;
    } else if (id < 114688) {  // mdiag
        int q = id - 98304;
        int o = q & 63;
        int t = (q >> 6) & 31;
        int b = q >> 11;
        const float* a1 = ws + OFF_A1 + ((size_t)b * 32 + t) * C10;
        const float* a0 = ws + OFF_A0 + (size_t)b * C5;
        float acc = b11[o] + b01[o];
        for (int m = 0; m < C10; ++m) acc += a1[m] * W11[m * NO + o];
        for (int m = 0; m < C5; ++m) acc += a0[m] * W01[m * NO + o];
        ws[OFF_MD + ((size_t)b * 32 + t) * NO + o] = acc;
    } else if (id < 116224) {  // r0
        int q = id - 114688;
        int o = q & 63;
        int b = (q >> 6) & 7;
        int i = q >> 9;
        const float* a0 = ws + OFF_A0 + (size_t)b * C5;
        float acc = b02[i * NO + o];
        for (int m = 0; m < C5; ++m) acc += a0[m] * W02[(size_t)i * C5 * NO + m * NO + o];
        ws[OFF_R0 + ((size_t)i * 8 + b) * NO + o] = acc;
    }
}

// ---------------------------------------------------------------------------
// K5 (main, MFMA): verified 2048x4 anchor (~46us, FETCH 79.7MB, WRITE 65.7MB).
// 8192x1 regresses (B-frag L2 traffic 4x — R8). UNCHANGED.
// ---------------------------------------------------------------------------
__global__ __launch_bounds__(256) void k_main(const float* __restrict__ x,
                                              const float* __restrict__ ws,
                                              const float* __restrict__ b33,
                                              float* __restrict__ T) {
    __shared__ __align__(16) unsigned short As[32 * 392];  // 392 = 384 + 8 pad
    int tid = threadIdx.x;
    const unsigned short* WB = (const unsigned short*)(ws + OFF_WB);

    int wv = tid >> 6;
    int lane = tid & 63;
    int m_tile = wv & 1;
    int n_pair = wv >> 1;
    int colq = lane & 15;
    int quad = lane >> 4;

    // B fragments once per block (L2-resident, coalesced dwordx4)
    short8 bfr[2][12];
#pragma unroll
    for (int np = 0; np < 2; ++np) {
        int nt = n_pair * 2 + np;
#pragma unroll
        for (int ks = 0; ks < 12; ++ks)
            bfr[np][ks] = *(const short8*)(WB + (size_t)((nt * 12 + ks) * 64 + lane) * 8);
    }
    float bb0 = b33[(n_pair * 2 + 0) * 16 + colq];
    float bb1 = b33[(n_pair * 2 + 1) * 16 + colq];

    int k0 = wv * 8;         // this wave's k-slab
    int c = colq * 4;        // channel offset (float4)
    int mrow = m_tile * 16 + colq;
    const unsigned short* Arow = &As[mrow * 392 + quad * 8];

    // XCD-chunked group-contiguous mapping (grid is exactly 2048 = 256 x 8)
    int tbase = (blockIdx.x & 7) * 1024 + (blockIdx.x >> 3) * 4;
#pragma unroll 1
    for (int r = 0; r < 4; ++r) {
        int tile = tbase + r;
        int b = tile >> 10;
        int i = (tile >> 5) & 31;
        int j = tile & 31;
        const float* xb = x + (size_t)b * 2097152;

        // stage: all 6 perms, p compile-time constant (wave-uniform path)
#pragma unroll
        for (int half = 0; half < 2; ++half) {
            int k = k0 + quad + half * 4;
            float4v v0 = *(const float4v*)(xb + i * 65536 + j * 2048 + k * 64 + c);
            float4v v1 = *(const float4v*)(xb + i * 65536 + k * 2048 + j * 64 + c);
            float4v v2 = *(const float4v*)(xb + j * 65536 + i * 2048 + k * 64 + c);
            float4v v3 = *(const float4v*)(xb + k * 65536 + i * 2048 + j * 64 + c);
            float4v v4 = *(const float4v*)(xb + j * 65536 + k * 2048 + i * 64 + c);
            float4v v5 = *(const float4v*)(xb + k * 65536 + j * 2048 + i * 64 + c);
            unsigned short* dst = &As[k * 392 + c];
            store_bf4(dst + 0 * 64, v0);
            store_bf4(dst + 1 * 64, v1);
            store_bf4(dst + 2 * 64, v2);
            store_bf4(dst + 3 * 64, v3);
            store_bf4(dst + 4 * 64, v4);
            store_bf4(dst + 5 * 64, v5);
        }
        __syncthreads();

        float4v acc0 = {0.f, 0.f, 0.f, 0.f};
        float4v acc1 = {0.f, 0.f, 0.f, 0.f};
#pragma unroll
        for (int ks = 0; ks < 12; ++ks) {
            short8 a = *(const short8*)(Arow + ks * 32);
            acc0 = __builtin_amdgcn_mfma_f32_16x16x32_bf16(a, bfr[0][ks], acc0, 0, 0, 0);
            acc1 = __builtin_amdgcn_mfma_f32_16x16x32_bf16(a, bfr[1][ks], acc1, 0, 0, 0);
        }

        float* Tb = T + (size_t)tile * 2048;
#pragma unroll
        for (int rr = 0; rr < 4; ++rr) {
            int m = m_tile * 16 + quad * 4 + rr;
            int o0 = (n_pair * 2 + 0) * 16 + colq;
            int o1 = (n_pair * 2 + 1) * 16 + colq;
            __builtin_nontemporal_store(acc0[rr] + bb0, &Tb[m * 64 + o0]);
            __builtin_nontemporal_store(acc1[rr] + bb1, &Tb[m * 64 + o1]);
        }
        __syncthreads();  // protect As before next tile's staging
    }
}

// ---------------------------------------------------------------------------
// K6 (slices, MFMA, fused expand): plane-split, 768 blocks = (i, b, t),
// 256 threads (4 waves). Verified in R9 (neutral vs 512-thread; kept).
// ---------------------------------------------------------------------------
__global__ __launch_bounds__(256) void k_slices(const float* __restrict__ b22,
                                                float* __restrict__ T,
                                                const float* __restrict__ ws) {
    __shared__ __align__(16) unsigned short As[32 * 776];  // 776 = 768 + 8 pad
    int blk = blockIdx.x;   // i*256 + b*32 + t
    int i = blk >> 8;       // plane 0..2
    int bt = blk & 255;
    int b = bt >> 5;
    int t = bt & 31;
    int tid = threadIdx.x;
    const unsigned short* abf = (const unsigned short*)(ws + OFF_ABF);
    const unsigned short* WB2 = (const unsigned short*)(ws + OFF_WB2);

    for (int l = tid; l < 3072; l += 256) {  // 3072 chunks of 8 shorts
        int d = l / 96;
        int m8 = l - d * 96;
        const unsigned short* src = (m8 < 48)
            ? abf + (size_t)(((b * 32 + t) * 32 + d) * C6) + m8 * 8
            : abf + (size_t)(((b * 32 + d) * 32 + t) * C6) + (m8 - 48) * 8;
        *(short8*)&As[d * 776 + m8 * 8] = *(const short8*)src;
    }
    __syncthreads();

    int wv = tid >> 6;
    int lane = tid & 63;
    int mt = wv & 1;   // 16 d-rows
    int nh = wv >> 1;  // o-tile pair (0..1)
    float4v zero = {0.f, 0.f, 0.f, 0.f};
    float4v acc[2] = {zero, zero};
    const unsigned short* Arow = &As[(mt * 16 + (lane & 15)) * 776 + (lane >> 4) * 8];
#pragma unroll
    for (int ks = 0; ks < 24; ++ks) {
        short8 a = *(const short8*)(Arow + ks * 32);
#pragma unroll
        for (int np = 0; np < 2; ++np) {
            int nt = nh * 2 + np;
            short8 bf = *(const short8*)(WB2 + (size_t)(((i * 4 + nt) * 24 + ks) * 64 + lane) * 8);
            acc[np] = __builtin_amdgcn_mfma_f32_16x16x32_bf16(a, bf, acc[np], 0, 0, 0);
        }
    }

    int colq = lane & 15;
    int quad = lane >> 4;
    float* Tb = T + (size_t)b * 2097152;
#pragma unroll
    for (int np = 0; np < 2; ++np) {
        int o = (nh * 2 + np) * 16 + colq;
        float base = b22[i * 64 + o] + ws[OFF_R1 + (((size_t)i * 8 + b) * 32 + t) * 64 + o]
                   + ws[OFF_R0 + ((size_t)i * 8 + b) * 64 + o];
#pragma unroll
        for (int r = 0; r < 4; ++r) {
            int d = mt * 16 + quad * 4 + r;
            float s = acc[np][r] + base +
                      ws[OFF_R1T + (((size_t)i * 8 + b) * 32 + d) * 64 + o];
            if (d != t) {
                size_t addr = (i == 0) ? (size_t)d * 65536 + d * 2048 + t * 64 + o
                            : (i == 1) ? (size_t)d * 65536 + t * 2048 + d * 64 + o
                                       : (size_t)t * 65536 + d * 2048 + d * 64 + o;
                Tb[addr] += s;
            } else {
                if (i == 0) s += ws[OFF_MD + ((size_t)b * 32 + d) * 64 + o];
                atomicAdd(&Tb[(size_t)d * 65536 + d * 2048 + d * 64 + o], s);
            }
        }
    }
}

// ---------------------------------------------------------------------------
extern "C" void kernel_launch(void* const* d_in, const int* in_sizes, int n_in,
                              void* d_out, int out_size, void* d_ws, size_t ws_size,
                              hipStream_t stream) {
    const float* x    = (const float*)d_in[0];
    const float* W33  = (const float*)d_in[1];
    const float* b33  = (const float*)d_in[2];
    const float* W22  = (const float*)d_in[3];
    const float* b22  = (const float*)d_in[4];
    const float* W12  = (const float*)d_in[5];
    const float* b12  = (const float*)d_in[6];
    const float* W12t = (const float*)d_in[7];
    const float* b12t = (const float*)d_in[8];
    const float* W02  = (const float*)d_in[9];
    const float* b02  = (const float*)d_in[10];
    const float* W11  = (const float*)d_in[11];
    const float* b11  = (const float*)d_in[12];
    const float* W01  = (const float*)d_in[13];
    const float* b01  = (const float*)d_in[14];
    float* T  = (float*)d_out;
    float* ws = (float*)d_ws;

    hipMemsetAsync(ws + OFF_A0, 0, (size_t)NBATCH * C5 * sizeof(float), stream);
    hipLaunchKernelGGL(k_prep2, dim3(1620), dim3(256), 0, stream, W33, W22, x, ws);
    hipLaunchKernelGGL(k_contract1, dim3(256), dim3(256), 0, stream, x, ws);
    hipLaunchKernelGGL(k_rowmix, dim3(454), dim3(256), 0, stream,
                       W12, b12, W12t, b12t, W02, b02, W11, b11, W01, b01, ws);
    hipLaunchKernelGGL(k_main, dim3(2048), dim3(256), 0, stream, x, ws, b33, T);
    hipLaunchKernelGGL(k_slices, dim3(768), dim3(256), 0, stream, b22, T, ws);
}

// Round 12
// 237.509 us; speedup vs baseline: 1.0544x; 1.0544x over previous
//
#include <hip/hip_runtime.h>

// SnConv3: B=8, N=32, C=64, O=64
#define NBATCH 8
#define NN 32
#define NC 64
#define NO 64
#define C6 384
#define C10 640
#define C12 768
#define C5 320

typedef __attribute__((ext_vector_type(8))) short short8;   // 8 bf16 (4 VGPRs)
typedef __attribute__((ext_vector_type(4))) float float4v;  // 4 fp32

// workspace layout (float offsets)
static constexpr int OFF_ABF = 0;        // a2 bf16 [8][32][32][384] = 1,572,864 floats
static constexpr int OFF_A1  = 1572864;  // [8][32][640] f32        =   163,840
static constexpr int OFF_A0  = 1736704;  // [8][320] f32            =     2,560
static constexpr int OFF_R1  = 1739264;  // [3][8][32][64]          =    49,152
static constexpr int OFF_R1T = 1788416;  // [3][8][32][64]          =    49,152
static constexpr int OFF_R0  = 1837568;  // [3][8][64]              =     1,536
static constexpr int OFF_MD  = 1839104;  // [8][32][64]             =    16,384
static constexpr int OFF_WB  = 1855488;  // W33 bf16 frags: 24576 sh =   12,288
static constexpr int OFF_WB2 = 1867776;  // W22 bf16 frags: 147456 sh=   73,728
// total 1,941,504 floats ~= 7.8 MB

__device__ __forceinline__ unsigned short f2bf(float f) {
    union { float f; unsigned u; } x{f};
    unsigned r = x.u + 0x7fffu + ((x.u >> 16) & 1u);  // RNE
    return (unsigned short)(r >> 16);
}

__device__ __forceinline__ void store_bf4(unsigned short* p, float4v v) {
    ushort4 w;
    w.x = f2bf(v.x); w.y = f2bf(v.y); w.z = f2bf(v.z); w.w = f2bf(v.w);
    *(ushort4*)p = w;
}

__device__ __forceinline__ float4v bf4(const unsigned short* p) {
    ushort4 u = *(const ushort4*)(p);
    float4v r;
    r.x = __uint_as_float((unsigned)u.x << 16);
    r.y = __uint_as_float((unsigned)u.y << 16);
    r.z = __uint_as_float((unsigned)u.z << 16);
    r.w = __uint_as_float((unsigned)u.w << 16);
    return r;
}

// ---------------------------------------------------------------------------
// K_prep2: fused weight-prep (blocks 0..83) + a2 contraction (blocks 84..1619),
// 3-way axis split (verified R11, neutral vs unsplit; kept).
// ---------------------------------------------------------------------------
__global__ __launch_bounds__(256) void k_prep2(const float* __restrict__ W33,
                                               const float* __restrict__ W22,
                                               const float* __restrict__ x,
                                               float* __restrict__ ws) {
    if (blockIdx.x < 84) {
        // ---- weight prep: W33/W22 f32 -> bf16 B-fragments ----
        int id = blockIdx.x * 256 + threadIdx.x;  // 21504
        if (id < 3072) {                          // W33: nt(4) x ks(12) x lane(64)
            int lane = id & 63;
            int ks = (id >> 6) % 12;
            int nt = (id >> 6) / 12;
            int n = nt * 16 + (lane & 15);
            int k0 = ks * 32 + (lane >> 4) * 8;
            unsigned short* dst = (unsigned short*)(ws + OFF_WB) +
                                  (size_t)((nt * 12 + ks) * 64 + lane) * 8;
#pragma unroll
            for (int jj = 0; jj < 8; ++jj) dst[jj] = f2bf(W33[(k0 + jj) * 64 + n]);
        } else if (id < 21504) {                  // W22: i(3) x nt(4) x ks(24) x lane(64)
            int q = id - 3072;
            int lane = q & 63;
            int ks = (q >> 6) % 24;
            int r = (q >> 6) / 24;
            int nt = r & 3;
            int i = r >> 2;
            int n = nt * 16 + (lane & 15);
            int k0 = ks * 32 + (lane >> 4) * 8;
            const float* W = W22 + (size_t)i * C12 * NO;
            unsigned short* dst = (unsigned short*)(ws + OFF_WB2) +
                                  (size_t)(((i * 4 + nt) * 24 + ks) * 64 + lane) * 8;
#pragma unroll
            for (int jj = 0; jj < 8; ++jj) dst[jj] = f2bf(W[(k0 + jj) * 64 + n]);
        }
        return;
    }
    // ---- a2 (bf16), 3-way axis split ----
    int qb = blockIdx.x - 84;              // 0..1535
    int cls = qb >> 9;                     // 0,1,2 (block-uniform)
    int id = (qb & 511) * 256 + threadIdx.x;  // 0..131071
    int c4 = id & 15;
    int v = (id >> 4) & 31;
    int u = (id >> 9) & 31;
    int b = id >> 14;
    int bc = c4 * 4;
    const float* xb = x + (size_t)b * 2097152;
    unsigned short* a2 = (unsigned short*)(ws + OFF_ABF) +
                         (size_t)((b * 32 + u) * 32 + v) * C6 + bc;
    const float inv = 1.0f / 32.0f;
    float4v s = {0.f, 0.f, 0.f, 0.f};

    if (cls == 0) {            // s1 = mean over axis1: x[b,i,u,v,c] ; d12 = x[b,v,v,u,c]
        const float* p = xb + u * 2048 + v * 64 + bc;
        for (int i = 0; i < 32; ++i) s += *(const float4v*)(p + i * 65536);
        float4v d12 = *(const float4v*)(xb + v * 65536 + v * 2048 + u * 64 + bc);
        store_bf4(a2 + 0 * 64, s * inv);
        store_bf4(a2 + 3 * 64, d12);
    } else if (cls == 1) {     // s2 = mean over axis2: x[b,u,j,v,c] ; d13 = x[b,v,u,v,c]
        const float* p = xb + u * 65536 + v * 64 + bc;
        for (int j = 0; j < 32; ++j) s += *(const float4v*)(p + j * 2048);
        float4v d13 = *(const float4v*)(xb + v * 65536 + u * 2048 + v * 64 + bc);
        store_bf4(a2 + 1 * 64, s * inv);
        store_bf4(a2 + 4 * 64, d13);
    } else {                   // s3 = mean over axis3: x[b,u,v,k,c] ; d23 = x[b,u,v,v,c]
        const float* p = xb + u * 65536 + v * 2048 + bc;
        for (int k = 0; k < 32; ++k) s += *(const float4v*)(p + k * 64);
        float4v d23 = *(const float4v*)(xb + u * 65536 + v * 2048 + v * 64 + bc);
        store_bf4(a2 + 2 * 64, s * inv);
        store_bf4(a2 + 5 * 64, d23);
    }
}

// ---------------------------------------------------------------------------
// K_contract1: a1 from bf16 a2 + triple diagonal, a0 atomics (pre-zeroed).
// Block per (b,t): 256 blocks x 256 threads. (Benched form, unchanged.)
// ---------------------------------------------------------------------------
__global__ __launch_bounds__(256) void k_contract1(const float* __restrict__ x,
                                                   float* __restrict__ ws) {
    __shared__ float4v red[16][148];  // [q][ch*16+c4], 4-f4 pad per q
    int blk = blockIdx.x;             // b*32 + t
    int b = blk >> 5;
    int t = blk & 31;
    int tid = threadIdx.x;
    int c4 = tid & 15;
    int q = tid >> 4;                 // 0..15
    int bc = c4 * 4;
    const unsigned short* a2 = (const unsigned short*)(ws + OFF_ABF) +
                               (size_t)b * 32 * 32 * C6;

    float4v pu0 = {0.f, 0.f, 0.f, 0.f};
    float4v pu3 = pu0, pu4 = pu0, pu5 = pu0;
    float4v pv0 = pu0, pv1 = pu0, pv3 = pu0, pv4 = pu0, pv5 = pu0;
#pragma unroll
    for (int s = 0; s < 2; ++s) {
        int u = q * 2 + s;
        const unsigned short* rU = a2 + (size_t)(u * 32 + t) * C6 + bc;
        const unsigned short* rV = a2 + (size_t)(t * 32 + u) * C6 + bc;
        pu0 += bf4(rU + 0);
        pu3 += bf4(rU + 192);
        pu4 += bf4(rU + 256);
        pu5 += bf4(rU + 320);
        pv0 += bf4(rV + 0);
        pv1 += bf4(rV + 64);
        pv3 += bf4(rV + 192);
        pv4 += bf4(rV + 256);
        pv5 += bf4(rV + 320);
    }
    // a1 chunk order: 0:su0 1:sv0 2:sv1 3:su3 4:sv3 5:su4 6:sv4 7:su5 8:sv5 9:td
    red[q][0 * 16 + c4] = pu0;
    red[q][1 * 16 + c4] = pv0;
    red[q][2 * 16 + c4] = pv1;
    red[q][3 * 16 + c4] = pu3;
    red[q][4 * 16 + c4] = pv3;
    red[q][5 * 16 + c4] = pu4;
    red[q][6 * 16 + c4] = pv4;
    red[q][7 * 16 + c4] = pu5;
    red[q][8 * 16 + c4] = pv5;
    __syncthreads();

    const float inv = 1.0f / 32.0f;
    float* a1 = ws + OFF_A1 + ((size_t)b * 32 + t) * C10;
    float* a0 = ws + OFF_A0 + (size_t)b * C5;
    if (tid < 144) {                  // 9 chunks x 16 c4
        int ch = tid >> 4;
        int cc = tid & 15;
        float4v s = {0.f, 0.f, 0.f, 0.f};
#pragma unroll
        for (int qq = 0; qq < 16; ++qq) s += red[qq][ch * 16 + cc];
        s *= inv;
        *(float4v*)(a1 + ch * 64 + cc * 4) = s;
        // a0 chunks: a1 {0,3,5,7} -> a0 {0,1,2,3}
        int aidx = (ch == 0) ? 0 : (ch == 3) ? 1 : (ch == 5) ? 2 : (ch == 7) ? 3 : -1;
        if (aidx >= 0) {
#pragma unroll
            for (int e = 0; e < 4; ++e)
                atomicAdd(a0 + aidx * 64 + cc * 4 + e, s[e] * inv);
        }
    } else if (tid < 160) {           // triple diagonal -> a1 chunk 9 + a0 chunk 4
        int cc = tid - 144;
        float4v td = *(const float4v*)(x + (((size_t)b * 32 + t) * 32 + t) * 2048 +
                                       t * 64 + cc * 4);
        *(float4v*)(a1 + 9 * 64 + cc * 4) = td;
#pragma unroll
        for (int e = 0; e < 4; ++e)
            atomicAdd(a0 + 4 * 64 + cc * 4 + e, td[e] * inv);
    }
}

// ---------------------------------------------------------------------------
// K_mainmix: rowmix (blocks 0..453) + k_main (blocks 454..2501) in ONE
// dispatch. The two halves are independent: rowmix needs a1/a0 (contract1,
// prior dispatch) and writes ws R1/R1T/R0/MD; k_main needs WB (prep2) + x and
// writes T. Rowmix blocks dispatch FIRST, so their ~10-30us of work co-runs
// UNDER k_main's 46us instead of serially before it. XCD-chunk property
// preserved: q=bid-454 => chunk {q&7=c} has constant bid&7=(c+6)&7.
// ---------------------------------------------------------------------------
__global__ __launch_bounds__(256) void k_mainmix(
    const float* __restrict__ x, const float* __restrict__ ws_c,
    const float* __restrict__ b33, float* __restrict__ T,
    const float* __restrict__ W12, const float* __restrict__ b12,
    const float* __restrict__ W12t, const float* __restrict__ b12t,
    const float* __restrict__ W02, const float* __restrict__ b02,
    const float* __restrict__ W11, const float* __restrict__ b11,
    const float* __restrict__ W01, const float* __restrict__ b01,
    float* __restrict__ ws) {
    __shared__ __align__(16) unsigned short As[32 * 392];  // 392 = 384 + 8 pad
    int tid = threadIdx.x;

    if (blockIdx.x < 454) {
        // ---- rowmix: r1, r1t, mdiag, r0 (116224 threads, TLP-optimal) ----
        int id = blockIdx.x * 256 + tid;
        if (id < 98304) {  // r1 / r1t
            bool second = id >= 49152;
            int q = second ? id - 49152 : id;
            int o = q & 63;
            int t = (q >> 6) & 31;
            int b = (q >> 11) & 7;
            int i = q >> 14;
            const float* W = (second ? W12t : W12) + (size_t)i * C10 * NO;
            const float* bb = (second ? b12t : b12) + i * NO;
            const float* a1 = ws + OFF_A1 + ((size_t)b * 32 + t) * C10;
            float acc = bb[o];
            for (int m = 0; m < C10; ++m) acc += a1[m] * W[m * NO + o];
            ws[(second ? OFF_R1T : OFF_R1) + (((size_t)i * 8 + b) * 32 + t) * NO + o] = acc;
        } else if (id < 114688) {  // mdiag
            int q = id - 98304;
            int o = q & 63;
            int t = (q >> 6) & 31;
            int b = q >> 11;
            const float* a1 = ws + OFF_A1 + ((size_t)b * 32 + t) * C10;
            const float* a0 = ws + OFF_A0 + (size_t)b * C5;
            float acc = b11[o] + b01[o];
            for (int m = 0; m < C10; ++m) acc += a1[m] * W11[m * NO + o];
            for (int m = 0; m < C5; ++m) acc += a0[m] * W01[m * NO + o];
            ws[OFF_MD + ((size_t)b * 32 + t) * NO + o] = acc;
        } else if (id < 116224) {  // r0
            int q = id - 114688;
            int o = q & 63;
            int b = (q >> 6) & 7;
            int i = q >> 9;
            const float* a0 = ws + OFF_A0 + (size_t)b * C5;
            float acc = b02[i * NO + o];
            for (int m = 0; m < C5; ++m) acc += a0[m] * W02[(size_t)i * C5 * NO + m * NO + o];
            ws[OFF_R0 + ((size_t)i * 8 + b) * NO + o] = acc;
        }
        return;
    }

    // ---- k_main: verified 2048x4 tile structure (anchor) ----
    const unsigned short* WB = (const unsigned short*)(ws_c + OFF_WB);

    int wv = tid >> 6;
    int lane = tid & 63;
    int m_tile = wv & 1;
    int n_pair = wv >> 1;
    int colq = lane & 15;
    int quad = lane >> 4;

    // B fragments once per block (L2-resident, coalesced dwordx4)
    short8 bfr[2][12];
#pragma unroll
    for (int np = 0; np < 2; ++np) {
        int nt = n_pair * 2 + np;
#pragma unroll
        for (int ks = 0; ks < 12; ++ks)
            bfr[np][ks] = *(const short8*)(WB + (size_t)((nt * 12 + ks) * 64 + lane) * 8);
    }
    float bb0 = b33[(n_pair * 2 + 0) * 16 + colq];
    float bb1 = b33[(n_pair * 2 + 1) * 16 + colq];

    int k0 = wv * 8;         // this wave's k-slab
    int c = colq * 4;        // channel offset (float4)
    int mrow = m_tile * 16 + colq;
    const unsigned short* Arow = &As[mrow * 392 + quad * 8];

    // XCD-chunked group-contiguous mapping over q = bid-454 (2048 = 256 x 8)
    int q = blockIdx.x - 454;
    int tbase = (q & 7) * 1024 + (q >> 3) * 4;
#pragma unroll 1
    for (int r = 0; r < 4; ++r) {
        int tile = tbase + r;
        int b = tile >> 10;
        int i = (tile >> 5) & 31;
        int j = tile & 31;
        const float* xb = x + (size_t)b * 2097152;

        // stage: all 6 perms, p compile-time constant (wave-uniform path)
#pragma unroll
        for (int half = 0; half < 2; ++half) {
            int k = k0 + quad + half * 4;
            float4v v0 = *(const float4v*)(xb + i * 65536 + j * 2048 + k * 64 + c);
            float4v v1 = *(const float4v*)(xb + i * 65536 + k * 2048 + j * 64 + c);
            float4v v2 = *(const float4v*)(xb + j * 65536 + i * 2048 + k * 64 + c);
            float4v v3 = *(const float4v*)(xb + k * 65536 + i * 2048 + j * 64 + c);
            float4v v4 = *(const float4v*)(xb + j * 65536 + k * 2048 + i * 64 + c);
            float4v v5 = *(const float4v*)(xb + k * 65536 + j * 2048 + i * 64 + c);
            unsigned short* dst = &As[k * 392 + c];
            store_bf4(dst + 0 * 64, v0);
            store_bf4(dst + 1 * 64, v1);
            store_bf4(dst + 2 * 64, v2);
            store_bf4(dst + 3 * 64, v3);
            store_bf4(dst + 4 * 64, v4);
            store_bf4(dst + 5 * 64, v5);
        }
        __syncthreads();

        float4v acc0 = {0.f, 0.f, 0.f, 0.f};
        float4v acc1 = {0.f, 0.f, 0.f, 0.f};
#pragma unroll
        for (int ks = 0; ks < 12; ++ks) {
            short8 a = *(const short8*)(Arow + ks * 32);
            acc0 = __builtin_amdgcn_mfma_f32_16x16x32_bf16(a, bfr[0][ks], acc0, 0, 0, 0);
            acc1 = __builtin_amdgcn_mfma_f32_16x16x32_bf16(a, bfr[1][ks], acc1, 0, 0, 0);
        }

        float* Tb = T + (size_t)tile * 2048;
#pragma unroll
        for (int rr = 0; rr < 4; ++rr) {
            int m = m_tile * 16 + quad * 4 + rr;
            int o0 = (n_pair * 2 + 0) * 16 + colq;
            int o1 = (n_pair * 2 + 1) * 16 + colq;
            __builtin_nontemporal_store(acc0[rr] + bb0, &Tb[m * 64 + o0]);
            __builtin_nontemporal_store(acc1[rr] + bb1, &Tb[m * 64 + o1]);
        }
        __syncthreads();  // protect As before next tile's staging
    }
}

// ---------------------------------------------------------------------------
// K6 (slices, MFMA, fused expand): plane-split, 768 blocks = (i, b, t),
// 256 threads (4 waves). Verified R9/R11.
// ---------------------------------------------------------------------------
__global__ __launch_bounds__(256) void k_slices(const float* __restrict__ b22,
                                                float* __restrict__ T,
                                                const float* __restrict__ ws) {
    __shared__ __align__(16) unsigned short As[32 * 776];  // 776 = 768 + 8 pad
    int blk = blockIdx.x;   // i*256 + b*32 + t
    int i = blk >> 8;       // plane 0..2
    int bt = blk & 255;
    int b = bt >> 5;
    int t = bt & 31;
    int tid = threadIdx.x;
    const unsigned short* abf = (const unsigned short*)(ws + OFF_ABF);
    const unsigned short* WB2 = (const unsigned short*)(ws + OFF_WB2);

    for (int l = tid; l < 3072; l += 256) {  // 3072 chunks of 8 shorts
        int d = l / 96;
        int m8 = l - d * 96;
        const unsigned short* src = (m8 < 48)
            ? abf + (size_t)(((b * 32 + t) * 32 + d) * C6) + m8 * 8
            : abf + (size_t)(((b * 32 + d) * 32 + t) * C6) + (m8 - 48) * 8;
        *(short8*)&As[d * 776 + m8 * 8] = *(const short8*)src;
    }
    __syncthreads();

    int wv = tid >> 6;
    int lane = tid & 63;
    int mt = wv & 1;   // 16 d-rows
    int nh = wv >> 1;  // o-tile pair (0..1)
    float4v zero = {0.f, 0.f, 0.f, 0.f};
    float4v acc[2] = {zero, zero};
    const unsigned short* Arow = &As[(mt * 16 + (lane & 15)) * 776 + (lane >> 4) * 8];
#pragma unroll
    for (int ks = 0; ks < 24; ++ks) {
        short8 a = *(const short8*)(Arow + ks * 32);
#pragma unroll
        for (int np = 0; np < 2; ++np) {
            int nt = nh * 2 + np;
            short8 bf = *(const short8*)(WB2 + (size_t)(((i * 4 + nt) * 24 + ks) * 64 + lane) * 8);
            acc[np] = __builtin_amdgcn_mfma_f32_16x16x32_bf16(a, bf, acc[np], 0, 0, 0);
        }
    }

    int colq = lane & 15;
    int quad = lane >> 4;
    float* Tb = T + (size_t)b * 2097152;
#pragma unroll
    for (int np = 0; np < 2; ++np) {
        int o = (nh * 2 + np) * 16 + colq;
        float base = b22[i * 64 + o] + ws[OFF_R1 + (((size_t)i * 8 + b) * 32 + t) * 64 + o]
                   + ws[OFF_R0 + ((size_t)i * 8 + b) * 64 + o];
#pragma unroll
        for (int r = 0; r < 4; ++r) {
            int d = mt * 16 + quad * 4 + r;
            float s = acc[np][r] + base +
                      ws[OFF_R1T + (((size_t)i * 8 + b) * 32 + d) * 64 + o];
            if (d != t) {
                size_t addr = (i == 0) ? (size_t)d * 65536 + d * 2048 + t * 64 + o
                            : (i == 1) ? (size_t)d * 65536 + t * 2048 + d * 64 + o
                                       : (size_t)t * 65536 + d * 2048 + d * 64 + o;
                Tb[addr] += s;
            } else {
                if (i == 0) s += ws[OFF_MD + ((size_t)b * 32 + d) * 64 + o];
                atomicAdd(&Tb[(size_t)d * 65536 + d * 2048 + d * 64 + o], s);
            }
        }
    }
}

// ---------------------------------------------------------------------------
extern "C" void kernel_launch(void* const* d_in, const int* in_sizes, int n_in,
                              void* d_out, int out_size, void* d_ws, size_t ws_size,
                              hipStream_t stream) {
    const float* x    = (const float*)d_in[0];
    const float* W33  = (const float*)d_in[1];
    const float* b33  = (const float*)d_in[2];
    const float* W22  = (const float*)d_in[3];
    const float* b22  = (const float*)d_in[4];
    const float* W12  = (const float*)d_in[5];
    const float* b12  = (const float*)d_in[6];
    const float* W12t = (const float*)d_in[7];
    const float* b12t = (const float*)d_in[8];
    const float* W02  = (const float*)d_in[9];
    const float* b02  = (const float*)d_in[10];
    const float* W11  = (const float*)d_in[11];
    const float* b11  = (const float*)d_in[12];
    const float* W01  = (const float*)d_in[13];
    const float* b01  = (const float*)d_in[14];
    float* T  = (float*)d_out;
    float* ws = (float*)d_ws;

    hipMemsetAsync(ws + OFF_A0, 0, (size_t)NBATCH * C5 * sizeof(float), stream);
    hipLaunchKernelGGL(k_prep2, dim3(1620), dim3(256), 0, stream, W33, W22, x, ws);
    hipLaunchKernelGGL(k_contract1, dim3(256), dim3(256), 0, stream, x, ws);
    hipLaunchKernelGGL(k_mainmix, dim3(2502), dim3(256), 0, stream,
                       x, ws, b33, T, W12, b12, W12t, b12t, W02, b02,
                       W11, b11, W01, b01, ws);
    hipLaunchKernelGGL(k_slices, dim3(768), dim3(256), 0, stream, b22, T, ws);
}